// Round 1
// baseline (586.231 us; speedup 1.0000x reference)
//
#include <hip/hip_runtime.h>
#include <hip/hip_bf16.h>

#define DEV __device__ __forceinline__

typedef short bf16x8 __attribute__((ext_vector_type(8)));
typedef float f32x4 __attribute__((ext_vector_type(4)));

constexpr int BB = 2, SS = 2048, DD = 1024, HH = 16, DHD = 64;
constexpr int MM = BB * SS; // 4096

DEV unsigned short f2bf(float f) {
    union { float f; unsigned int u; } v; v.f = f;
    return (unsigned short)((v.u + 0x7fffu + ((v.u >> 16) & 1u)) >> 16);
}

DEV bf16x8 ld_bf16x8(const unsigned short* p) { return *(const bf16x8*)p; }

// ---- prep: Wt[n][k] = bf16(W[k][n]) ----
__global__ void transpose_w(const float* __restrict__ W, unsigned short* __restrict__ Wt) {
    __shared__ float tile[32][33];
    int n0 = blockIdx.x * 32, k0 = blockIdx.y * 32;
    int tx = threadIdx.x, ty = threadIdx.y; // 32 x 8
    #pragma unroll
    for (int i = 0; i < 4; ++i)
        tile[ty + 8 * i][tx] = W[(size_t)(k0 + ty + 8 * i) * DD + n0 + tx];
    __syncthreads();
    #pragma unroll
    for (int i = 0; i < 4; ++i)
        Wt[(size_t)(n0 + ty + 8 * i) * DD + k0 + tx] = f2bf(tile[tx][ty + 8 * i]);
}

// ---- QKV projection: Y = x @ W + b ; writes Q(scaled), K as [B,H,S,DH], V as [B,H,DH,S] ----
__global__ __launch_bounds__(256, 2) void qkv_gemm(
    const float* __restrict__ x,
    const unsigned short* __restrict__ WtBase,
    const float* __restrict__ bq, const float* __restrict__ bk, const float* __restrict__ bv,
    unsigned short* __restrict__ Qb, unsigned short* __restrict__ Kb, unsigned short* __restrict__ Vt)
{
    const int z = blockIdx.z;
    const unsigned short* Wt = WtBase + (size_t)z * DD * DD;
    const float* bias = (z == 0) ? bq : (z == 1) ? bk : bv;

    const int m0 = blockIdx.y * 64;
    const int n0 = blockIdx.x * 128;
    const int wave = threadIdx.x >> 6;
    const int lane = threadIdx.x & 63;
    const int quad = lane >> 4;
    const int lcol = lane & 15;
    const int mbase = m0 + 32 * (wave & 1);
    const int nbase = n0 + 64 * (wave >> 1);

    f32x4 acc[2][4];
    #pragma unroll
    for (int i = 0; i < 2; ++i)
        #pragma unroll
        for (int j = 0; j < 4; ++j) acc[i][j] = (f32x4){0.f, 0.f, 0.f, 0.f};

    for (int k0 = 0; k0 < DD; k0 += 32) {
        bf16x8 afr[2];
        #pragma unroll
        for (int mi = 0; mi < 2; ++mi) {
            const float* ap = x + (size_t)(mbase + 16 * mi + lcol) * DD + k0 + quad * 8;
            float4 a0 = *(const float4*)ap;
            float4 a1 = *(const float4*)(ap + 4);
            union { bf16x8 v; unsigned short u[8]; } af;
            af.u[0] = f2bf(a0.x); af.u[1] = f2bf(a0.y); af.u[2] = f2bf(a0.z); af.u[3] = f2bf(a0.w);
            af.u[4] = f2bf(a1.x); af.u[5] = f2bf(a1.y); af.u[6] = f2bf(a1.z); af.u[7] = f2bf(a1.w);
            afr[mi] = af.v;
        }
        bf16x8 bfr[4];
        #pragma unroll
        for (int ni = 0; ni < 4; ++ni)
            bfr[ni] = ld_bf16x8(Wt + (size_t)(nbase + 16 * ni + lcol) * DD + k0 + quad * 8);
        #pragma unroll
        for (int mi = 0; mi < 2; ++mi)
            #pragma unroll
            for (int ni = 0; ni < 4; ++ni)
                acc[mi][ni] = __builtin_amdgcn_mfma_f32_16x16x32_bf16(afr[mi], bfr[ni], acc[mi][ni], 0, 0, 0);
    }

    #pragma unroll
    for (int mi = 0; mi < 2; ++mi)
        #pragma unroll
        for (int ni = 0; ni < 4; ++ni)
            #pragma unroll
            for (int r = 0; r < 4; ++r) {
                int m = mbase + 16 * mi + quad * 4 + r;
                int n = nbase + 16 * ni + lcol;
                float v = acc[mi][ni][r] + bias[n];
                int b = m >> 11, s = m & (SS - 1);
                int h = n >> 6, dh = n & 63;
                if (z == 0)
                    Qb[(((size_t)b * HH + h) * SS + s) * DHD + dh] = f2bf(v * 0.125f); // fold 1/sqrt(DH)
                else if (z == 1)
                    Kb[(((size_t)b * HH + h) * SS + s) * DHD + dh] = f2bf(v);
                else
                    Vt[(((size_t)b * HH + h) * DHD + dh) * SS + s] = f2bf(v);
            }
}

// ---- attention: one block = 16 q-rows x one (b,h); full 2048-key softmax, scores in registers ----
__global__ __launch_bounds__(256, 2) void attn(
    const unsigned short* __restrict__ Qb,
    const unsigned short* __restrict__ Kb,
    const unsigned short* __restrict__ Vt,
    unsigned short* __restrict__ Ob)
{
    __shared__ unsigned short P[32768]; // 64 KiB; blocked layout [kb=col/16][row][col%16]
    float* redf = (float*)P;            // aliased reduction scratch (overwritten before P writes)

    const int qt = blockIdx.x;
    const int bh = blockIdx.y;
    const int b = bh >> 4, h = bh & (HH - 1);
    const unsigned short* Qbh = Qb + (size_t)bh * SS * DHD;
    const unsigned short* Kbh = Kb + (size_t)bh * SS * DHD;
    const unsigned short* Vbh = Vt + (size_t)bh * DHD * SS;

    const int wave = threadIdx.x >> 6, lane = threadIdx.x & 63;
    const int quad = lane >> 4, lcol = lane & 15;

    // Q A-frags (k = dh), scale already folded in
    bf16x8 qf0 = ld_bf16x8(Qbh + (size_t)(qt * 16 + lcol) * DHD + quad * 8);
    bf16x8 qf1 = ld_bf16x8(Qbh + (size_t)(qt * 16 + lcol) * DHD + 32 + quad * 8);

    // scores: this wave covers keys [wave*512, wave*512+512)
    f32x4 sc[32];
    #pragma unroll
    for (int t = 0; t < 32; ++t) {
        const unsigned short* kp = Kbh + (size_t)(wave * 512 + t * 16 + lcol) * DHD + quad * 8;
        bf16x8 kf0 = ld_bf16x8(kp);
        bf16x8 kf1 = ld_bf16x8(kp + 32);
        f32x4 c = (f32x4){0.f, 0.f, 0.f, 0.f};
        c = __builtin_amdgcn_mfma_f32_16x16x32_bf16(qf0, kf0, c, 0, 0, 0);
        c = __builtin_amdgcn_mfma_f32_16x16x32_bf16(qf1, kf1, c, 0, 0, 0);
        sc[t] = c;
    }

    // row max: per-lane over tiles, shuffle across the 16 lanes of the quad, LDS across waves
    float pm[4];
    #pragma unroll
    for (int r = 0; r < 4; ++r) pm[r] = sc[0][r];
    #pragma unroll
    for (int t = 1; t < 32; ++t)
        #pragma unroll
        for (int r = 0; r < 4; ++r) pm[r] = fmaxf(pm[r], sc[t][r]);
    #pragma unroll
    for (int msk = 1; msk < 16; msk <<= 1)
        #pragma unroll
        for (int r = 0; r < 4; ++r) pm[r] = fmaxf(pm[r], __shfl_xor(pm[r], msk, 64));
    if (lcol == 0) {
        #pragma unroll
        for (int r = 0; r < 4; ++r) redf[wave * 16 + quad * 4 + r] = pm[r];
    }
    __syncthreads();
    float rm[4];
    #pragma unroll
    for (int r = 0; r < 4; ++r) {
        int row = quad * 4 + r;
        rm[r] = fmaxf(fmaxf(redf[row], redf[16 + row]), fmaxf(redf[32 + row], redf[48 + row]));
    }

    // exp + row sum
    float ps[4] = {0.f, 0.f, 0.f, 0.f};
    #pragma unroll
    for (int t = 0; t < 32; ++t)
        #pragma unroll
        for (int r = 0; r < 4; ++r) {
            float e = __expf(sc[t][r] - rm[r]);
            sc[t][r] = e;
            ps[r] += e;
        }
    #pragma unroll
    for (int msk = 1; msk < 16; msk <<= 1)
        #pragma unroll
        for (int r = 0; r < 4; ++r) ps[r] += __shfl_xor(ps[r], msk, 64);
    if (lcol == 0) {
        #pragma unroll
        for (int r = 0; r < 4; ++r) redf[64 + wave * 16 + quad * 4 + r] = ps[r];
    }
    __syncthreads();
    float rinv[4];
    #pragma unroll
    for (int r = 0; r < 4; ++r) {
        int row = quad * 4 + r;
        rinv[r] = 1.0f / (redf[64 + row] + redf[80 + row] + redf[96 + row] + redf[112 + row]);
    }
    __syncthreads(); // all redf reads complete before P overwrites the aliased bytes

    // write normalized P (bf16) into blocked LDS layout
    #pragma unroll
    for (int t = 0; t < 32; ++t) {
        int kb = wave * 32 + t;
        #pragma unroll
        for (int r = 0; r < 4; ++r)
            P[kb * 256 + (quad * 4 + r) * 16 + lcol] = f2bf(sc[t][r] * rinv[r]);
    }
    __syncthreads();

    // PV: this wave computes O cols dh = wave*16 + lcol over all 2048 keys
    f32x4 oacc = (f32x4){0.f, 0.f, 0.f, 0.f};
    const int dh = wave * 16 + lcol;
    #pragma unroll 8
    for (int kk = 0; kk < 64; ++kk) {
        // A-frag: P[m=lcol][k = kk*32 + quad*8 + j]  (blocked addressing)
        bf16x8 pf = *(const bf16x8*)&P[(kk * 2 + (quad >> 1)) * 256 + lcol * 16 + (quad & 1) * 8];
        // B-frag: V[k=skey][n=dh] = Vt[dh][skey], contiguous in skey
        bf16x8 vf = ld_bf16x8(Vbh + (size_t)dh * SS + kk * 32 + quad * 8);
        oacc = __builtin_amdgcn_mfma_f32_16x16x32_bf16(pf, vf, oacc, 0, 0, 0);
    }
    #pragma unroll
    for (int r = 0; r < 4; ++r) {
        int srow = qt * 16 + quad * 4 + r;
        // Ob layout [B, S, H, DH] == [M, D] row-major for the final GEMM
        Ob[(((size_t)b * SS + srow) * HH + h) * DHD + dh] = f2bf(oacc[r]);
    }
}

// ---- output projection: out = Ob @ Wo + bo (fp32 out) ----
__global__ __launch_bounds__(256, 2) void out_gemm(
    const unsigned short* __restrict__ Ob,
    const unsigned short* __restrict__ Wto,
    const float* __restrict__ bo,
    float* __restrict__ out)
{
    const int m0 = blockIdx.y * 64;
    const int n0 = blockIdx.x * 128;
    const int wave = threadIdx.x >> 6;
    const int lane = threadIdx.x & 63;
    const int quad = lane >> 4;
    const int lcol = lane & 15;
    const int mbase = m0 + 32 * (wave & 1);
    const int nbase = n0 + 64 * (wave >> 1);

    f32x4 acc[2][4];
    #pragma unroll
    for (int i = 0; i < 2; ++i)
        #pragma unroll
        for (int j = 0; j < 4; ++j) acc[i][j] = (f32x4){0.f, 0.f, 0.f, 0.f};

    for (int k0 = 0; k0 < DD; k0 += 32) {
        bf16x8 afr[2];
        #pragma unroll
        for (int mi = 0; mi < 2; ++mi)
            afr[mi] = ld_bf16x8(Ob + (size_t)(mbase + 16 * mi + lcol) * DD + k0 + quad * 8);
        bf16x8 bfr[4];
        #pragma unroll
        for (int ni = 0; ni < 4; ++ni)
            bfr[ni] = ld_bf16x8(Wto + (size_t)(nbase + 16 * ni + lcol) * DD + k0 + quad * 8);
        #pragma unroll
        for (int mi = 0; mi < 2; ++mi)
            #pragma unroll
            for (int ni = 0; ni < 4; ++ni)
                acc[mi][ni] = __builtin_amdgcn_mfma_f32_16x16x32_bf16(afr[mi], bfr[ni], acc[mi][ni], 0, 0, 0);
    }

    #pragma unroll
    for (int mi = 0; mi < 2; ++mi)
        #pragma unroll
        for (int ni = 0; ni < 4; ++ni)
            #pragma unroll
            for (int r = 0; r < 4; ++r) {
                int m = mbase + 16 * mi + quad * 4 + r;
                int n = nbase + 16 * ni + lcol;
                out[(size_t)m * DD + n] = acc[mi][ni][r] + bo[n];
            }
}

extern "C" void kernel_launch(void* const* d_in, const int* in_sizes, int n_in,
                              void* d_out, int out_size, void* d_ws, size_t ws_size,
                              hipStream_t stream)
{
    const float* x  = (const float*)d_in[0];
    const float* Wq = (const float*)d_in[1];
    const float* bq = (const float*)d_in[2];
    const float* Wk = (const float*)d_in[3];
    const float* bk = (const float*)d_in[4];
    const float* Wv = (const float*)d_in[5];
    const float* bv = (const float*)d_in[6];
    const float* Wo = (const float*)d_in[7];
    const float* bo = (const float*)d_in[8];
    float* out = (float*)d_out;

    unsigned short* ws = (unsigned short*)d_ws;
    unsigned short* Wtq = ws;                        // D*D each
    unsigned short* Wtk = Wtq + (size_t)DD * DD;
    unsigned short* Wtv = Wtk + (size_t)DD * DD;
    unsigned short* Wto = Wtv + (size_t)DD * DD;
    unsigned short* Qb  = Wto + (size_t)DD * DD;     // M*D each
    unsigned short* Kb  = Qb  + (size_t)MM * DD;
    unsigned short* Vt  = Kb  + (size_t)MM * DD;
    unsigned short* Ob  = Vt  + (size_t)MM * DD;     // total 40 MB

    dim3 tb(32, 8);
    dim3 tg(DD / 32, DD / 32);
    transpose_w<<<tg, tb, 0, stream>>>(Wq, Wtq);
    transpose_w<<<tg, tb, 0, stream>>>(Wk, Wtk);
    transpose_w<<<tg, tb, 0, stream>>>(Wv, Wtv);
    transpose_w<<<tg, tb, 0, stream>>>(Wo, Wto);

    qkv_gemm<<<dim3(DD / 128, MM / 64, 3), 256, 0, stream>>>(x, Wtq, bq, bk, bv, Qb, Kb, Vt);

    attn<<<dim3(SS / 16, BB * HH), 256, 0, stream>>>(Qb, Kb, Vt, Ob);

    out_gemm<<<dim3(DD / 128, MM / 64), 256, 0, stream>>>(Ob, Wto, bo, out);
}

// Round 2
// 509.744 us; speedup vs baseline: 1.1501x; 1.1501x over previous
//
#include <hip/hip_runtime.h>
#include <hip/hip_bf16.h>

#define DEV __device__ __forceinline__

typedef short bf16x8 __attribute__((ext_vector_type(8)));
typedef float f32x4 __attribute__((ext_vector_type(4)));

constexpr int BB = 2, SS = 2048, DD = 1024, HH = 16, DHD = 64;
constexpr int MM = BB * SS; // 4096

DEV unsigned short f2bf(float f) {
    union { float f; unsigned int u; } v; v.f = f;
    return (unsigned short)((v.u + 0x7fffu + ((v.u >> 16) & 1u)) >> 16);
}

DEV bf16x8 ld_bf16x8(const unsigned short* p) { return *(const bf16x8*)p; }

// ---- prep: xb = bf16(x), vectorized ----
__global__ void x2bf(const float* __restrict__ x, unsigned short* __restrict__ xb) {
    int i = blockIdx.x * 256 + threadIdx.x;
    float4 v = ((const float4*)x)[i];
    ushort4 o;
    o.x = f2bf(v.x); o.y = f2bf(v.y); o.z = f2bf(v.z); o.w = f2bf(v.w);
    ((ushort4*)xb)[i] = o;
}

// ---- prep: Wt[n][k] = bf16(W[k][n]) for all 4 weights in one launch ----
__global__ void transpose_w4(const float* __restrict__ W0, const float* __restrict__ W1,
                             const float* __restrict__ W2, const float* __restrict__ W3,
                             unsigned short* __restrict__ WtBase) {
    __shared__ float tile[32][33];
    const float* W = (blockIdx.z == 0) ? W0 : (blockIdx.z == 1) ? W1 : (blockIdx.z == 2) ? W2 : W3;
    unsigned short* Wt = WtBase + (size_t)blockIdx.z * DD * DD;
    int n0 = blockIdx.x * 32, k0 = blockIdx.y * 32;
    int tx = threadIdx.x, ty = threadIdx.y; // 32 x 8
    #pragma unroll
    for (int i = 0; i < 4; ++i)
        tile[ty + 8 * i][tx] = W[(size_t)(k0 + ty + 8 * i) * DD + n0 + tx];
    __syncthreads();
    #pragma unroll
    for (int i = 0; i < 4; ++i)
        Wt[(size_t)(n0 + ty + 8 * i) * DD + k0 + tx] = f2bf(tile[tx][ty + 8 * i]);
}

// ---- QKV projection: Y = xb @ W + b ; writes Q(scaled), K as [B,H,S,DH], V as [B,H,DH,S] ----
__global__ __launch_bounds__(256, 4) void qkv_gemm(
    const unsigned short* __restrict__ xb,
    const unsigned short* __restrict__ WtBase,
    const float* __restrict__ bq, const float* __restrict__ bk, const float* __restrict__ bv,
    unsigned short* __restrict__ Qb, unsigned short* __restrict__ Kb, unsigned short* __restrict__ Vt)
{
    const int z = blockIdx.z;
    const unsigned short* Wt = WtBase + (size_t)z * DD * DD;
    const float* bias = (z == 0) ? bq : (z == 1) ? bk : bv;

    const int m0 = blockIdx.y * 64;
    const int n0 = blockIdx.x * 128;
    const int wave = threadIdx.x >> 6;
    const int lane = threadIdx.x & 63;
    const int quad = lane >> 4;
    const int lcol = lane & 15;
    const int mbase = m0 + 32 * (wave & 1);
    const int nbase = n0 + 64 * (wave >> 1);

    f32x4 acc[2][4];
    #pragma unroll
    for (int i = 0; i < 2; ++i)
        #pragma unroll
        for (int j = 0; j < 4; ++j) acc[i][j] = (f32x4){0.f, 0.f, 0.f, 0.f};

    for (int k0 = 0; k0 < DD; k0 += 32) {
        bf16x8 afr[2];
        #pragma unroll
        for (int mi = 0; mi < 2; ++mi)
            afr[mi] = ld_bf16x8(xb + (size_t)(mbase + 16 * mi + lcol) * DD + k0 + quad * 8);
        bf16x8 bfr[4];
        #pragma unroll
        for (int ni = 0; ni < 4; ++ni)
            bfr[ni] = ld_bf16x8(Wt + (size_t)(nbase + 16 * ni + lcol) * DD + k0 + quad * 8);
        #pragma unroll
        for (int mi = 0; mi < 2; ++mi)
            #pragma unroll
            for (int ni = 0; ni < 4; ++ni)
                acc[mi][ni] = __builtin_amdgcn_mfma_f32_16x16x32_bf16(afr[mi], bfr[ni], acc[mi][ni], 0, 0, 0);
    }

    #pragma unroll
    for (int mi = 0; mi < 2; ++mi)
        #pragma unroll
        for (int ni = 0; ni < 4; ++ni)
            #pragma unroll
            for (int r = 0; r < 4; ++r) {
                int m = mbase + 16 * mi + quad * 4 + r;
                int n = nbase + 16 * ni + lcol;
                float v = acc[mi][ni][r] + bias[n];
                int b = m >> 11, s = m & (SS - 1);
                int h = n >> 6, dh = n & 63;
                if (z == 0)
                    Qb[(((size_t)b * HH + h) * SS + s) * DHD + dh] = f2bf(v * 0.125f); // fold 1/sqrt(DH)
                else if (z == 1)
                    Kb[(((size_t)b * HH + h) * SS + s) * DHD + dh] = f2bf(v);
                else
                    Vt[(((size_t)b * HH + h) * DHD + dh) * SS + s] = f2bf(v);
            }
}

// ---- attention v2: streaming, shared-scalar-max softmax, deferred normalization ----
// block = 16 q-rows x one (b,h); wave w handles keys [w*512, w*512+512)
__global__ __launch_bounds__(256, 4) void attn(
    const unsigned short* __restrict__ Qb,
    const unsigned short* __restrict__ Kb,
    const unsigned short* __restrict__ Vt,
    unsigned short* __restrict__ Ob)
{
    // padded transpose buffer: row stride 40 shorts (80B) -> 2-way bank aliasing (free)
    __shared__ __align__(16) unsigned short tbuf[4][2][16][40];
    __shared__ float Obuf[4][16][66]; // padded: 66-float rows -> conflict-light
    __shared__ float lsum[4][16];
    __shared__ float mred[4];

    const int qt = blockIdx.x;
    const int bh = blockIdx.y;
    const int b = bh >> 4, h = bh & (HH - 1);
    const unsigned short* Qbh = Qb + (size_t)bh * SS * DHD;
    const unsigned short* Kbh = Kb + (size_t)bh * SS * DHD;
    const unsigned short* Vbh = Vt + (size_t)bh * DHD * SS;

    const int wave = threadIdx.x >> 6, lane = threadIdx.x & 63;
    const int quad = lane >> 4, lcol = lane & 15;

    // Q A-frags (k = dh); 1/sqrt(DH) already folded into Q
    const unsigned short* Qp = Qbh + (size_t)(qt * 16 + lcol) * DHD;
    bf16x8 qf0 = ld_bf16x8(Qp + quad * 8);
    bf16x8 qf1 = ld_bf16x8(Qp + 32 + quad * 8);

    // ---- block-scalar max estimate from each wave's first 32-key chunk ----
    // softmax(s - m0) is exact for ANY m0; overshoot only costs exp range, and
    // scores are bounded (|s| <= |q||k|/8 ~ O(10)) so exp stays in fp32 range.
    {
        const unsigned short* kp = Kbh + (size_t)(wave * 512 + lcol) * DHD + quad * 8;
        f32x4 s0 = (f32x4){0.f, 0.f, 0.f, 0.f}, s1 = (f32x4){0.f, 0.f, 0.f, 0.f};
        s0 = __builtin_amdgcn_mfma_f32_16x16x32_bf16(qf0, ld_bf16x8(kp), s0, 0, 0, 0);
        s0 = __builtin_amdgcn_mfma_f32_16x16x32_bf16(qf1, ld_bf16x8(kp + 32), s0, 0, 0, 0);
        s1 = __builtin_amdgcn_mfma_f32_16x16x32_bf16(qf0, ld_bf16x8(kp + 16 * DHD), s1, 0, 0, 0);
        s1 = __builtin_amdgcn_mfma_f32_16x16x32_bf16(qf1, ld_bf16x8(kp + 16 * DHD + 32), s1, 0, 0, 0);
        float mm = s0[0];
        #pragma unroll
        for (int r = 1; r < 4; ++r) mm = fmaxf(mm, s0[r]);
        #pragma unroll
        for (int r = 0; r < 4; ++r) mm = fmaxf(mm, s1[r]);
        #pragma unroll
        for (int msk = 1; msk < 64; msk <<= 1) mm = fmaxf(mm, __shfl_xor(mm, msk, 64));
        if (lane == 0) mred[wave] = mm;
    }
    __syncthreads();
    const float m0 = fmaxf(fmaxf(mred[0], mred[1]), fmaxf(mred[2], mred[3]));

    // ---- stream 16 chunks of 32 keys: QK -> exp -> LDS transpose -> PV ----
    f32x4 oacc[4];
    #pragma unroll
    for (int ni = 0; ni < 4; ++ni) oacc[ni] = (f32x4){0.f, 0.f, 0.f, 0.f};
    float ps[4] = {0.f, 0.f, 0.f, 0.f};

    #pragma unroll 2
    for (int c = 0; c < 16; ++c) {
        const int kb = wave * 512 + c * 32;
        const unsigned short* kp = Kbh + (size_t)(kb + lcol) * DHD + quad * 8;
        f32x4 t0 = (f32x4){0.f, 0.f, 0.f, 0.f}, t1 = (f32x4){0.f, 0.f, 0.f, 0.f};
        t0 = __builtin_amdgcn_mfma_f32_16x16x32_bf16(qf0, ld_bf16x8(kp), t0, 0, 0, 0);
        t0 = __builtin_amdgcn_mfma_f32_16x16x32_bf16(qf1, ld_bf16x8(kp + 32), t0, 0, 0, 0);
        t1 = __builtin_amdgcn_mfma_f32_16x16x32_bf16(qf0, ld_bf16x8(kp + 16 * DHD), t1, 0, 0, 0);
        t1 = __builtin_amdgcn_mfma_f32_16x16x32_bf16(qf1, ld_bf16x8(kp + 16 * DHD + 32), t1, 0, 0, 0);

        unsigned short* tw = &tbuf[wave][c & 1][0][0];
        #pragma unroll
        for (int r = 0; r < 4; ++r) {
            float e0 = __expf(t0[r] - m0);
            float e1 = __expf(t1[r] - m0);
            ps[r] += e0 + e1;
            tw[(quad * 4 + r) * 40 + lcol] = f2bf(e0);        // P[q][key kb+lcol]
            tw[(quad * 4 + r) * 40 + 16 + lcol] = f2bf(e1);   // P[q][key kb+16+lcol]
        }
        // wave-private LDS: DS pipe is in-order per wave -> read sees the writes
        bf16x8 pf = *(const bf16x8*)&tbuf[wave][c & 1][lcol][quad * 8]; // A[m=lcol][k=quad*8+j]
        #pragma unroll
        for (int ni = 0; ni < 4; ++ni) {
            bf16x8 vf = ld_bf16x8(Vbh + (size_t)(ni * 16 + lcol) * SS + kb + quad * 8);
            oacc[ni] = __builtin_amdgcn_mfma_f32_16x16x32_bf16(pf, vf, oacc[ni], 0, 0, 0);
        }
    }

    // ---- epilogue: cross-wave reduce of unnormalized O and l ----
    #pragma unroll
    for (int msk = 1; msk < 16; msk <<= 1)
        #pragma unroll
        for (int r = 0; r < 4; ++r) ps[r] += __shfl_xor(ps[r], msk, 64);
    if (lcol == 0) {
        #pragma unroll
        for (int r = 0; r < 4; ++r) lsum[wave][quad * 4 + r] = ps[r];
    }
    #pragma unroll
    for (int ni = 0; ni < 4; ++ni)
        #pragma unroll
        for (int r = 0; r < 4; ++r)
            Obuf[wave][quad * 4 + r][ni * 16 + lcol] = oacc[ni][r];
    __syncthreads();

    const int t = threadIdx.x;
    const int row = t >> 4;            // 4 elems/thread: elem idx = t*4
    const int dh0 = (t & 15) * 4;
    float l = lsum[0][row] + lsum[1][row] + lsum[2][row] + lsum[3][row];
    float inv = 1.0f / l;
    ushort4 o;
    float v0 = (Obuf[0][row][dh0 + 0] + Obuf[1][row][dh0 + 0] + Obuf[2][row][dh0 + 0] + Obuf[3][row][dh0 + 0]) * inv;
    float v1 = (Obuf[0][row][dh0 + 1] + Obuf[1][row][dh0 + 1] + Obuf[2][row][dh0 + 1] + Obuf[3][row][dh0 + 1]) * inv;
    float v2 = (Obuf[0][row][dh0 + 2] + Obuf[1][row][dh0 + 2] + Obuf[2][row][dh0 + 2] + Obuf[3][row][dh0 + 2]) * inv;
    float v3 = (Obuf[0][row][dh0 + 3] + Obuf[1][row][dh0 + 3] + Obuf[2][row][dh0 + 3] + Obuf[3][row][dh0 + 3]) * inv;
    o.x = f2bf(v0); o.y = f2bf(v1); o.z = f2bf(v2); o.w = f2bf(v3);
    // Ob layout [B, S, H, DH] == [M, D] row-major for the final GEMM
    *(ushort4*)&Ob[(((size_t)b * SS + qt * 16 + row) * HH + h) * DHD + dh0] = o;
}

// ---- output projection: out = Ob @ Wo + bo (fp32 out) ----
__global__ __launch_bounds__(256, 4) void out_gemm(
    const unsigned short* __restrict__ Ob,
    const unsigned short* __restrict__ Wto,
    const float* __restrict__ bo,
    float* __restrict__ out)
{
    const int m0 = blockIdx.y * 64;
    const int n0 = blockIdx.x * 128;
    const int wave = threadIdx.x >> 6;
    const int lane = threadIdx.x & 63;
    const int quad = lane >> 4;
    const int lcol = lane & 15;
    const int mbase = m0 + 32 * (wave & 1);
    const int nbase = n0 + 64 * (wave >> 1);

    f32x4 acc[2][4];
    #pragma unroll
    for (int i = 0; i < 2; ++i)
        #pragma unroll
        for (int j = 0; j < 4; ++j) acc[i][j] = (f32x4){0.f, 0.f, 0.f, 0.f};

    for (int k0 = 0; k0 < DD; k0 += 32) {
        bf16x8 afr[2];
        #pragma unroll
        for (int mi = 0; mi < 2; ++mi)
            afr[mi] = ld_bf16x8(Ob + (size_t)(mbase + 16 * mi + lcol) * DD + k0 + quad * 8);
        bf16x8 bfr[4];
        #pragma unroll
        for (int ni = 0; ni < 4; ++ni)
            bfr[ni] = ld_bf16x8(Wto + (size_t)(nbase + 16 * ni + lcol) * DD + k0 + quad * 8);
        #pragma unroll
        for (int mi = 0; mi < 2; ++mi)
            #pragma unroll
            for (int ni = 0; ni < 4; ++ni)
                acc[mi][ni] = __builtin_amdgcn_mfma_f32_16x16x32_bf16(afr[mi], bfr[ni], acc[mi][ni], 0, 0, 0);
    }

    #pragma unroll
    for (int mi = 0; mi < 2; ++mi)
        #pragma unroll
        for (int ni = 0; ni < 4; ++ni)
            #pragma unroll
            for (int r = 0; r < 4; ++r) {
                int m = mbase + 16 * mi + quad * 4 + r;
                int n = nbase + 16 * ni + lcol;
                out[(size_t)m * DD + n] = acc[mi][ni][r] + bo[n];
            }
}

extern "C" void kernel_launch(void* const* d_in, const int* in_sizes, int n_in,
                              void* d_out, int out_size, void* d_ws, size_t ws_size,
                              hipStream_t stream)
{
    const float* x  = (const float*)d_in[0];
    const float* Wq = (const float*)d_in[1];
    const float* bq = (const float*)d_in[2];
    const float* Wk = (const float*)d_in[3];
    const float* bk = (const float*)d_in[4];
    const float* Wv = (const float*)d_in[5];
    const float* bv = (const float*)d_in[6];
    const float* Wo = (const float*)d_in[7];
    const float* bo = (const float*)d_in[8];
    float* out = (float*)d_out;

    unsigned short* ws = (unsigned short*)d_ws;
    unsigned short* Wt  = ws;                        // 4 * D*D (q,k,v,o)
    unsigned short* Wto = Wt + 3 * (size_t)DD * DD;
    unsigned short* Qb  = Wt + 4 * (size_t)DD * DD;  // M*D each
    unsigned short* Kb  = Qb + (size_t)MM * DD;
    unsigned short* Vt  = Kb + (size_t)MM * DD;
    unsigned short* xb  = Vt + (size_t)MM * DD;      // total 40 MB
    unsigned short* Ob  = xb;                        // alias: xb dead after qkv_gemm

    x2bf<<<MM * DD / 4 / 256, 256, 0, stream>>>(x, xb);
    transpose_w4<<<dim3(DD / 32, DD / 32, 4), dim3(32, 8), 0, stream>>>(Wq, Wk, Wv, Wo, Wt);

    qkv_gemm<<<dim3(DD / 128, MM / 64, 3), 256, 0, stream>>>(xb, Wt, bq, bk, bv, Qb, Kb, Vt);

    attn<<<dim3(SS / 16, BB * HH), 256, 0, stream>>>(Qb, Kb, Vt, Ob);

    out_gemm<<<dim3(DD / 128, MM / 64), 256, 0, stream>>>(Ob, Wto, bo, out);
}

// Round 3
// 215.884 us; speedup vs baseline: 2.7155x; 2.3612x over previous
//
#include <hip/hip_runtime.h>
#include <hip/hip_bf16.h>

#define DEV __device__ __forceinline__

typedef short bf16x8 __attribute__((ext_vector_type(8)));
typedef float f32x4 __attribute__((ext_vector_type(4)));
typedef unsigned int u32;

constexpr int BB = 2, SS = 2048, DD = 1024, HH = 16, DHD = 64;
constexpr int MM = BB * SS; // 4096

DEV unsigned short f2bf(float f) {
    union { float f; unsigned int u; } v; v.f = f;
    return (unsigned short)((v.u + 0x7fffu + ((v.u >> 16) & 1u)) >> 16);
}

DEV bf16x8 ld_bf16x8(const unsigned short* p) { return *(const bf16x8*)p; }

// async global->LDS, 16B per lane; lds dest = wave-uniform base + lane*16
DEV void gl16(const unsigned short* g, unsigned short* l) {
    __builtin_amdgcn_global_load_lds(
        (const __attribute__((address_space(1))) u32*)g,
        (__attribute__((address_space(3))) u32*)l, 16, 0, 0);
}

// ---- prep: xb = bf16(x) ----
__global__ void x2bf(const float* __restrict__ x, unsigned short* __restrict__ xb) {
    int i = blockIdx.x * 256 + threadIdx.x;
    float4 v = ((const float4*)x)[i];
    ushort4 o;
    o.x = f2bf(v.x); o.y = f2bf(v.y); o.z = f2bf(v.z); o.w = f2bf(v.w);
    ((ushort4*)xb)[i] = o;
}

// ---- prep: Wt[n][k] = bf16(W[k][n]) for all 4 weights ----
__global__ void transpose_w4(const float* __restrict__ W0, const float* __restrict__ W1,
                             const float* __restrict__ W2, const float* __restrict__ W3,
                             unsigned short* __restrict__ WtBase) {
    __shared__ float tile[32][33];
    const float* W = (blockIdx.z == 0) ? W0 : (blockIdx.z == 1) ? W1 : (blockIdx.z == 2) ? W2 : W3;
    unsigned short* Wt = WtBase + (size_t)blockIdx.z * DD * DD;
    int n0 = blockIdx.x * 32, k0 = blockIdx.y * 32;
    int tx = threadIdx.x, ty = threadIdx.y; // 32 x 8
    #pragma unroll
    for (int i = 0; i < 4; ++i)
        tile[ty + 8 * i][tx] = W[(size_t)(k0 + ty + 8 * i) * DD + n0 + tx];
    __syncthreads();
    #pragma unroll
    for (int i = 0; i < 4; ++i)
        Wt[(size_t)(n0 + ty + 8 * i) * DD + k0 + tx] = f2bf(tile[tx][ty + 8 * i]);
}

// ====================== QKV GEMM (m97-style, 128x128 tile) ======================
// LDS tile layout: 16B block idx = row*4 + (part ^ (row&3)); part = 8 bf16 of k
__global__ __launch_bounds__(256) void qkv_gemm(
    const unsigned short* __restrict__ xb,
    const unsigned short* __restrict__ WtBase,
    const float* __restrict__ bq, const float* __restrict__ bk, const float* __restrict__ bv,
    unsigned short* __restrict__ Qb, unsigned short* __restrict__ Kb, unsigned short* __restrict__ Vt)
{
    __shared__ __align__(16) unsigned short Ald[2][128 * 32];
    __shared__ __align__(16) unsigned short Bld[2][128 * 32];

    const int z = blockIdx.z;
    const unsigned short* Wt = WtBase + (size_t)z * DD * DD;
    const float* bias = (z == 0) ? bq : (z == 1) ? bk : bv;

    const int m0g = blockIdx.y * 128;
    const int n0g = blockIdx.x * 128;
    const int wave = threadIdx.x >> 6, lane = threadIdx.x & 63;
    const int quad = lane >> 4, lcol = lane & 15;
    const int mb = (wave & 1) * 64, nb = (wave >> 1) * 64;

    f32x4 acc[4][4];
    #pragma unroll
    for (int i = 0; i < 4; ++i)
        #pragma unroll
        for (int j = 0; j < 4; ++j) acc[i][j] = (f32x4){0.f, 0.f, 0.f, 0.f};

    auto stage = [&](int ks, int bf) {
        #pragma unroll
        for (int i = 0; i < 4; ++i) {
            int j = wave * 4 + i;
            if (j < 8) { // A: xb rows m0g..m0g+127
                int bi = j * 64 + lane;
                int row = bi >> 2, p = (bi & 3) ^ (row & 3);
                gl16(xb + (size_t)(m0g + row) * DD + ks + p * 8, &Ald[bf][j * 512]);
            } else {     // B: Wt rows n0g..n0g+127
                int jj = j - 8;
                int bi = jj * 64 + lane;
                int row = bi >> 2, p = (bi & 3) ^ (row & 3);
                gl16(Wt + (size_t)(n0g + row) * DD + ks + p * 8, &Bld[bf][jj * 512]);
            }
        }
    };

    stage(0, 0);
    __syncthreads();

    for (int kk = 0; kk < 32; ++kk) {
        int bf = kk & 1;
        if (kk + 1 < 32) stage((kk + 1) * 32, (kk + 1) & 1);
        bf16x8 af[4], bfr[4];
        #pragma unroll
        for (int mt = 0; mt < 4; ++mt) {
            int row = mb + mt * 16 + lcol;
            af[mt] = ld_bf16x8(&Ald[bf][(row * 4 + (quad ^ (row & 3))) * 8]);
        }
        #pragma unroll
        for (int nt = 0; nt < 4; ++nt) {
            int row = nb + nt * 16 + lcol;
            bfr[nt] = ld_bf16x8(&Bld[bf][(row * 4 + (quad ^ (row & 3))) * 8]);
        }
        #pragma unroll
        for (int mt = 0; mt < 4; ++mt)
            #pragma unroll
            for (int nt = 0; nt < 4; ++nt)
                acc[mt][nt] = __builtin_amdgcn_mfma_f32_16x16x32_bf16(af[mt], bfr[nt], acc[mt][nt], 0, 0, 0);
        __syncthreads();
    }

    #pragma unroll
    for (int mt = 0; mt < 4; ++mt)
        #pragma unroll
        for (int nt = 0; nt < 4; ++nt) {
            int n = n0g + nb + nt * 16 + lcol;
            float bv_ = bias[n];
            int h = n >> 6, dh = n & 63;
            #pragma unroll
            for (int r = 0; r < 4; ++r) {
                int m = m0g + mb + mt * 16 + quad * 4 + r;
                float v = acc[mt][nt][r] + bv_;
                int b = m >> 11, s = m & (SS - 1);
                if (z == 0)
                    Qb[(((size_t)b * HH + h) * SS + s) * DHD + dh] = f2bf(v * 0.125f); // fold 1/sqrt(DH)
                else if (z == 1)
                    Kb[(((size_t)b * HH + h) * SS + s) * DHD + dh] = f2bf(v);
                else
                    Vt[(((size_t)b * HH + h) * DHD + dh) * SS + s] = f2bf(v);
            }
        }
}

// ====================== attention v3 ======================
// block = 128 q-rows x one (b,h); wave owns 32 rows over ALL 2048 keys.
// K/V chunks (64 keys) staged to LDS via global_load_lds, XOR-swizzled 16B blocks.
// Computes S^T = K.Q^T so P-transpose is a packed b64 write into per-wave tbuf.
__global__ __launch_bounds__(256) void attn(
    const unsigned short* __restrict__ Qb,
    const unsigned short* __restrict__ Kb,
    const unsigned short* __restrict__ Vt,
    unsigned short* __restrict__ Ob)
{
    __shared__ __align__(16) unsigned short Kld[2][64 * 64]; // keys x dh, swizzled blocks
    __shared__ __align__(16) unsigned short Vld[2][64 * 64]; // dh x keys, swizzled blocks
    __shared__ __align__(16) unsigned short tb[4][2][16 * 72]; // [wave][mtile][row][72]

    const int qt = blockIdx.x;   // 16 tiles of 128 rows
    const int bh = blockIdx.y;
    const int b = bh >> 4, h = bh & (HH - 1);
    const unsigned short* Qbh = Qb + (size_t)bh * SS * DHD;
    const unsigned short* Kbh = Kb + (size_t)bh * SS * DHD;
    const unsigned short* Vbh = Vt + (size_t)bh * DHD * SS;

    const int wave = threadIdx.x >> 6, lane = threadIdx.x & 63;
    const int quad = lane >> 4, lcol = lane & 15;
    const int rowbase = qt * 128 + wave * 32;

    // Q B-frags (n = q-row, k = dh); 1/sqrt(DH) folded into Q
    bf16x8 qf[2][2];
    #pragma unroll
    for (int mt = 0; mt < 2; ++mt)
        #pragma unroll
        for (int kf = 0; kf < 2; ++kf)
            qf[mt][kf] = ld_bf16x8(Qbh + (size_t)(rowbase + mt * 16 + lcol) * DHD + kf * 32 + quad * 8);

    auto stage = [&](int c, int bf) {
        int kb = c * 64;
        #pragma unroll
        for (int i = 0; i < 4; ++i) {
            int j = wave * 4 + i;
            if (j < 8) { // K: rows = keys, 8 parts of dh
                int bi = j * 64 + lane;
                int r = bi >> 3, p = (bi & 7) ^ (r & 7);
                gl16(Kbh + (size_t)(kb + r) * DHD + p * 8, &Kld[bf][j * 512]);
            } else {     // V: rows = dh, 8 parts of keys
                int jj = j - 8;
                int bi = jj * 64 + lane;
                int dh = bi >> 3, p = (bi & 7) ^ (dh & 7);
                gl16(Vbh + (size_t)dh * SS + kb + p * 8, &Vld[bf][jj * 512]);
            }
        }
    };

    // ---- prologue: stage chunk 0, estimate wave-uniform m0 from it ----
    stage(0, 0);
    __syncthreads();

    float m0 = -1e30f;
    #pragma unroll
    for (int kt = 0; kt < 4; ++kt) {
        int r0 = kt * 16 + lcol;
        bf16x8 ka0 = ld_bf16x8(&Kld[0][(r0 * 8 + (quad ^ (r0 & 7))) * 8]);
        bf16x8 ka1 = ld_bf16x8(&Kld[0][(r0 * 8 + ((quad + 4) ^ (r0 & 7))) * 8]);
        #pragma unroll
        for (int mt = 0; mt < 2; ++mt) {
            f32x4 s = (f32x4){0.f, 0.f, 0.f, 0.f};
            s = __builtin_amdgcn_mfma_f32_16x16x32_bf16(ka0, qf[mt][0], s, 0, 0, 0);
            s = __builtin_amdgcn_mfma_f32_16x16x32_bf16(ka1, qf[mt][1], s, 0, 0, 0);
            #pragma unroll
            for (int r = 0; r < 4; ++r) m0 = fmaxf(m0, s[r]);
        }
    }
    #pragma unroll
    for (int msk = 1; msk < 64; msk <<= 1) m0 = fmaxf(m0, __shfl_xor(m0, msk, 64));

    // ---- main loop over 32 chunks of 64 keys ----
    f32x4 oacc[2][4];
    #pragma unroll
    for (int mt = 0; mt < 2; ++mt)
        #pragma unroll
        for (int nt = 0; nt < 4; ++nt) oacc[mt][nt] = (f32x4){0.f, 0.f, 0.f, 0.f};
    float ps[2] = {0.f, 0.f};

    for (int c = 0; c < 32; ++c) {
        int bf = c & 1;
        if (c + 1 < 32) stage(c + 1, (c + 1) & 1);

        // S^T = K.Q^T -> exp -> packed b64 write into tbuf [q-row][key]
        #pragma unroll
        for (int kt = 0; kt < 4; ++kt) {
            int r0 = kt * 16 + lcol;
            bf16x8 ka0 = ld_bf16x8(&Kld[bf][(r0 * 8 + (quad ^ (r0 & 7))) * 8]);
            bf16x8 ka1 = ld_bf16x8(&Kld[bf][(r0 * 8 + ((quad + 4) ^ (r0 & 7))) * 8]);
            #pragma unroll
            for (int mt = 0; mt < 2; ++mt) {
                f32x4 s = (f32x4){0.f, 0.f, 0.f, 0.f};
                s = __builtin_amdgcn_mfma_f32_16x16x32_bf16(ka0, qf[mt][0], s, 0, 0, 0);
                s = __builtin_amdgcn_mfma_f32_16x16x32_bf16(ka1, qf[mt][1], s, 0, 0, 0);
                float e0 = __expf(s[0] - m0), e1 = __expf(s[1] - m0);
                float e2 = __expf(s[2] - m0), e3 = __expf(s[3] - m0);
                ps[mt] += (e0 + e1) + (e2 + e3);
                u32 lo = ((u32)f2bf(e1) << 16) | f2bf(e0);
                u32 hi = ((u32)f2bf(e3) << 16) | f2bf(e2);
                *(uint2*)&tb[wave][mt][lcol * 72 + kt * 16 + quad * 4] = make_uint2(lo, hi);
            }
        }

        // PV: A = P (from tbuf), B = V (from Vld)
        #pragma unroll
        for (int kf2 = 0; kf2 < 2; ++kf2) {
            bf16x8 vb[4];
            #pragma unroll
            for (int nt = 0; nt < 4; ++nt) {
                int dh = nt * 16 + lcol;
                vb[nt] = ld_bf16x8(&Vld[bf][(dh * 8 + ((kf2 * 4 + quad) ^ (dh & 7))) * 8]);
            }
            #pragma unroll
            for (int mt = 0; mt < 2; ++mt) {
                bf16x8 pa = *(const bf16x8*)&tb[wave][mt][lcol * 72 + kf2 * 32 + quad * 8];
                #pragma unroll
                for (int nt = 0; nt < 4; ++nt)
                    oacc[mt][nt] = __builtin_amdgcn_mfma_f32_16x16x32_bf16(pa, vb[nt], oacc[mt][nt], 0, 0, 0);
            }
        }
        __syncthreads();
    }

    // ---- epilogue: per-row normalize (rows owned entirely by this wave) ----
    #pragma unroll
    for (int mt = 0; mt < 2; ++mt) {
        ps[mt] += __shfl_xor(ps[mt], 16, 64);
        ps[mt] += __shfl_xor(ps[mt], 32, 64);
    }
    float inv[2] = {1.0f / ps[0], 1.0f / ps[1]};
    #pragma unroll
    for (int mt = 0; mt < 2; ++mt)
        #pragma unroll
        for (int r = 0; r < 4; ++r) {
            float iv = __shfl(inv[mt], quad * 4 + r, 64); // inv lives at lane lcol == row
            int srow = rowbase + mt * 16 + quad * 4 + r;
            size_t base = (((size_t)b * SS + srow) * HH + h) * DHD;
            #pragma unroll
            for (int nt = 0; nt < 4; ++nt)
                Ob[base + nt * 16 + lcol] = f2bf(oacc[mt][nt][r] * iv);
        }
}

// ====================== output GEMM (64x128 tile) ======================
__global__ __launch_bounds__(256) void out_gemm(
    const unsigned short* __restrict__ Ob,
    const unsigned short* __restrict__ Wto,
    const float* __restrict__ bo,
    float* __restrict__ out)
{
    __shared__ __align__(16) unsigned short Ald[2][64 * 32];
    __shared__ __align__(16) unsigned short Bld[2][128 * 32];

    const int m0g = blockIdx.y * 64;
    const int n0g = blockIdx.x * 128;
    const int wave = threadIdx.x >> 6, lane = threadIdx.x & 63;
    const int quad = lane >> 4, lcol = lane & 15;
    const int nb = wave * 32;

    f32x4 acc[4][2];
    #pragma unroll
    for (int i = 0; i < 4; ++i)
        #pragma unroll
        for (int j = 0; j < 2; ++j) acc[i][j] = (f32x4){0.f, 0.f, 0.f, 0.f};

    auto stage = [&](int ks, int bf) {
        #pragma unroll
        for (int i = 0; i < 3; ++i) {
            int j = wave * 3 + i;
            if (j < 4) { // A: Ob rows m0g..m0g+63
                int bi = j * 64 + lane;
                int row = bi >> 2, p = (bi & 3) ^ (row & 3);
                gl16(Ob + (size_t)(m0g + row) * DD + ks + p * 8, &Ald[bf][j * 512]);
            } else {     // B: Wto rows n0g..n0g+127
                int jj = j - 4;
                int bi = jj * 64 + lane;
                int row = bi >> 2, p = (bi & 3) ^ (row & 3);
                gl16(Wto + (size_t)(n0g + row) * DD + ks + p * 8, &Bld[bf][jj * 512]);
            }
        }
    };

    stage(0, 0);
    __syncthreads();

    for (int kk = 0; kk < 32; ++kk) {
        int bf = kk & 1;
        if (kk + 1 < 32) stage((kk + 1) * 32, (kk + 1) & 1);
        bf16x8 af[4], bfr[2];
        #pragma unroll
        for (int mt = 0; mt < 4; ++mt) {
            int row = mt * 16 + lcol;
            af[mt] = ld_bf16x8(&Ald[bf][(row * 4 + (quad ^ (row & 3))) * 8]);
        }
        #pragma unroll
        for (int nt = 0; nt < 2; ++nt) {
            int row = nb + nt * 16 + lcol;
            bfr[nt] = ld_bf16x8(&Bld[bf][(row * 4 + (quad ^ (row & 3))) * 8]);
        }
        #pragma unroll
        for (int mt = 0; mt < 4; ++mt)
            #pragma unroll
            for (int nt = 0; nt < 2; ++nt)
                acc[mt][nt] = __builtin_amdgcn_mfma_f32_16x16x32_bf16(af[mt], bfr[nt], acc[mt][nt], 0, 0, 0);
        __syncthreads();
    }

    #pragma unroll
    for (int mt = 0; mt < 4; ++mt)
        #pragma unroll
        for (int nt = 0; nt < 2; ++nt) {
            int n = n0g + nb + nt * 16 + lcol;
            float bv_ = bo[n];
            #pragma unroll
            for (int r = 0; r < 4; ++r) {
                int m = m0g + mt * 16 + quad * 4 + r;
                out[(size_t)m * DD + n] = acc[mt][nt][r] + bv_;
            }
        }
}

extern "C" void kernel_launch(void* const* d_in, const int* in_sizes, int n_in,
                              void* d_out, int out_size, void* d_ws, size_t ws_size,
                              hipStream_t stream)
{
    const float* x  = (const float*)d_in[0];
    const float* Wq = (const float*)d_in[1];
    const float* bq = (const float*)d_in[2];
    const float* Wk = (const float*)d_in[3];
    const float* bk = (const float*)d_in[4];
    const float* Wv = (const float*)d_in[5];
    const float* bv = (const float*)d_in[6];
    const float* Wo = (const float*)d_in[7];
    const float* bo = (const float*)d_in[8];
    float* out = (float*)d_out;

    unsigned short* ws = (unsigned short*)d_ws;
    unsigned short* Wt  = ws;                        // 4 * D*D (q,k,v,o)
    unsigned short* Wto = Wt + 3 * (size_t)DD * DD;
    unsigned short* Qb  = Wt + 4 * (size_t)DD * DD;  // M*D each
    unsigned short* Kb  = Qb + (size_t)MM * DD;
    unsigned short* Vt  = Kb + (size_t)MM * DD;
    unsigned short* xb  = Vt + (size_t)MM * DD;      // total 40 MB
    unsigned short* Ob  = xb;                        // alias: xb dead after qkv_gemm

    x2bf<<<MM * DD / 4 / 256, 256, 0, stream>>>(x, xb);
    transpose_w4<<<dim3(DD / 32, DD / 32, 4), dim3(32, 8), 0, stream>>>(Wq, Wk, Wv, Wo, Wt);

    qkv_gemm<<<dim3(DD / 128, MM / 128, 3), 256, 0, stream>>>(xb, Wt, bq, bk, bv, Qb, Kb, Vt);

    attn<<<dim3(SS / 128, BB * HH), 256, 0, stream>>>(Qb, Kb, Vt, Ob);

    out_gemm<<<dim3(DD / 128, MM / 64), 256, 0, stream>>>(Ob, Wto, bo, out);
}